// Round 8
// baseline (479.331 us; speedup 1.0000x reference)
//
#include <hip/hip_runtime.h>

#define NN 512
#define MM 512
#define NEO 510
#define PLANE (NN * MM)          // 262144
#define STATE_CH 26
#define OUT_DIM 28
#define FEAT 245
#define NW (FEAT * OUT_DIM)      // 6860
#define THRESH 0.0007f
#define TI 4                      // rows per block
#define TJ 64                     // cols per block

// Fused prologue. blockIdx.x < 256: transpose state0 -> planar A and B.
// blockIdx.x >= 256: W12 = W1@W2, b12 = b1@W2+b2.
__global__ __launch_bounds__(256) void prep_all(
    const float* __restrict__ s0, float* __restrict__ A, float* __restrict__ B,
    const float* __restrict__ W1, const float* __restrict__ b1,
    const float* __restrict__ W2, const float* __restrict__ b2,
    float* __restrict__ W12, float* __restrict__ b12) {
  if (blockIdx.x < 256) {
    const int base = (blockIdx.x * 256 + threadIdx.x) * 4;  // 4 consecutive cells
    float v[4][STATE_CH];
    const float* src = s0 + (size_t)base * STATE_CH;
#pragma unroll
    for (int q = 0; q < 4; ++q)
#pragma unroll
      for (int c = 0; c < STATE_CH; ++c) v[q][c] = src[q * STATE_CH + c];
#pragma unroll
    for (int c = 0; c < STATE_CH; ++c) {
      float4 w = make_float4(v[0][c], v[1][c], v[2][c], v[3][c]);
      *(float4*)(A + (size_t)c * PLANE + base) = w;
      *(float4*)(B + (size_t)c * PLANE + base) = w;
    }
  } else {
    const int t = (blockIdx.x - 256) * 256 + threadIdx.x;
    if (t < NW) {
      const int f = t / OUT_DIM, k = t - f * OUT_DIM;
      float s = 0.0f;
      for (int jj = 0; jj < FEAT; ++jj) s = fmaf(W1[f * FEAT + jj], W2[jj * OUT_DIM + k], s);
      W12[t] = s;
    } else if (t < NW + OUT_DIM) {
      const int k = t - NW;
      float s = b2[k];
      for (int jj = 0; jj < FEAT; ++jj) s = fmaf(b1[jj], W2[jj * OUT_DIM + k], s);
      b12[k] = s;
    }
  }
}

template <bool LAST>
__global__ __launch_bounds__(256, 2) void nca_step(
    const float* __restrict__ img, const float* __restrict__ sold, float* __restrict__ snew,
    const int* __restrict__ pold, int* __restrict__ pnew,
    const float* __restrict__ W12, const float* __restrict__ b12,
    float* __restrict__ out0, float* __restrict__ out1) {
  // state tile (incl. +2 halo): 26*6*66*4 = 41184 B; weights: 27440 B -> 68.6 KB, 2 blocks/CU
  __shared__ float lds[STATE_CH][TI + 2][TJ + 2];
  __shared__ __align__(16) float wlds[NW];
  const int lane = (int)(threadIdx.x & 63);
  const int wv   = (int)(threadIdx.x >> 6);
  const int j0 = blockIdx.x * TJ;
  const int i0 = blockIdx.y * TI;

  // ---- stage weights -> LDS (coalesced, 27 iters/thread) ----
  for (int t = (int)threadIdx.x; t < NW; t += 256) wlds[t] = W12[t];

  // ---- stage state tile -> LDS (coalesced 64-lane rows) ----
  for (int pp = wv; pp < STATE_CH * (TI + 2); pp += 4) {
    const int ch = pp / (TI + 2);
    const int row = pp - ch * (TI + 2);
    const int gi = i0 + row;
    float v0 = 0.0f, v1 = 0.0f;
    if (gi < NN) {
      const float* src = sold + (size_t)ch * PLANE + gi * MM + j0;
      v0 = src[lane];
      if (lane < 2 && j0 + 64 + lane < MM) v1 = src[64 + lane];
    }
    lds[ch][row][lane] = v0;
    if (lane < 2) lds[ch][row][64 + lane] = v1;
  }
  __syncthreads();

  const int j = j0 + lane;
  const int i = i0 + wv;
  if (i >= NEO || j >= NEO) return;
  const int cell = i * NEO + j;
  const int2 p = ((const int2*)pold)[cell];

  float acc[OUT_DIM];
#pragma unroll
  for (int k = 0; k < OUT_DIM; ++k) acc[k] = b12[k];

#pragma unroll 1
  for (int di = 0; di < 3; ++di) {
#pragma unroll 1
    for (int dj = 0; dj < 3; ++dj) {
      float vals[27];
      vals[0] = img[(p.x + di) * MM + (p.y + dj)];
#pragma unroll
      for (int c = 0; c < STATE_CH; ++c) vals[1 + c] = lds[c][wv + di][lane + dj];
      const int wbase = (di * 3 + dj) * 27 * OUT_DIM;
#pragma unroll
      for (int t = 0; t < 27; ++t) {
        const float vt = vals[t];
        const float4* wr = (const float4*)&wlds[wbase + t * OUT_DIM];
#pragma unroll
        for (int r = 0; r < 7; ++r) {
          float4 w4 = wr[r];
          acc[4 * r + 0] = fmaf(vt, w4.x, acc[4 * r + 0]);
          acc[4 * r + 1] = fmaf(vt, w4.y, acc[4 * r + 1]);
          acc[4 * r + 2] = fmaf(vt, w4.z, acc[4 * r + 2]);
          acc[4 * r + 3] = fmaf(vt, w4.w, acc[4 * r + 3]);
        }
      }
    }
  }
  const float posx = (float)(p.x - 256) * (1.0f / 256.0f);
  const float posy = (float)(p.y - 256) * (1.0f / 256.0f);
  {
    const float4* wr = (const float4*)&wlds[243 * OUT_DIM];
#pragma unroll
    for (int r = 0; r < 7; ++r) {
      float4 w4 = wr[r];
      acc[4 * r + 0] = fmaf(posx, w4.x, acc[4 * r + 0]);
      acc[4 * r + 1] = fmaf(posx, w4.y, acc[4 * r + 1]);
      acc[4 * r + 2] = fmaf(posx, w4.z, acc[4 * r + 2]);
      acc[4 * r + 3] = fmaf(posx, w4.w, acc[4 * r + 3]);
    }
    const float4* wr2 = (const float4*)&wlds[244 * OUT_DIM];
#pragma unroll
    for (int r = 0; r < 7; ++r) {
      float4 w4 = wr2[r];
      acc[4 * r + 0] = fmaf(posy, w4.x, acc[4 * r + 0]);
      acc[4 * r + 1] = fmaf(posy, w4.y, acc[4 * r + 1]);
      acc[4 * r + 2] = fmaf(posy, w4.z, acc[4 * r + 2]);
      acc[4 * r + 3] = fmaf(posy, w4.w, acc[4 * r + 3]);
    }
  }

  const int nb = (i + 1) * MM + (j + 1);   // global addr for snew write
  if (!LAST) {
    const float ax = acc[26], ay = acc[27];
    int dx = (ax < -THRESH) ? -1 : ((ax > THRESH) ? 1 : 0);
    int dy = (ay < -THRESH) ? -1 : ((ay > THRESH) ? 1 : 0);
    int nx = min(max(p.x + dx, 0), NEO - 1);
    int ny = min(max(p.y + dy, 0), NEO - 1);
    ((int2*)pnew)[cell] = make_int2(nx, ny);
#pragma unroll
    for (int c = 0; c < STATE_CH; ++c)
      snew[c * PLANE + nb] = lds[c][wv + 1][lane + 1] + acc[c];
  } else {
    // out0: final state slice channels 16..25, layout [i][j][c10]
    float2* o0 = (float2*)(out0 + (size_t)cell * 10);
#pragma unroll
    for (int c = 0; c < 5; ++c) {
      float2 v;
      v.x = lds[16 + 2 * c][wv + 1][lane + 1] + acc[16 + 2 * c];
      v.y = lds[17 + 2 * c][wv + 1][lane + 1] + acc[17 + 2 * c];
      o0[c] = v;
    }
    // out1: final guesses, layout [cell][28]
    float4* o1 = (float4*)(out1 + (size_t)cell * OUT_DIM);
#pragma unroll
    for (int q = 0; q < 7; ++q)
      o1[q] = make_float4(acc[4 * q], acc[4 * q + 1], acc[4 * q + 2], acc[4 * q + 3]);
  }
}

extern "C" void kernel_launch(void* const* d_in, const int* in_sizes, int n_in,
                              void* d_out, int out_size, void* d_ws, size_t ws_size,
                              hipStream_t stream) {
  const float* img    = (const float*)d_in[0];
  const float* state0 = (const float*)d_in[1];
  const int*   perc0  = (const int*)d_in[2];
  const float* W1     = (const float*)d_in[3];
  const float* b1     = (const float*)d_in[4];
  const float* W2     = (const float*)d_in[5];
  const float* b2     = (const float*)d_in[6];
  float* out = (float*)d_out;

  float* stateA = (float*)d_ws;                              // 26*PLANE f32
  float* stateB = stateA + (size_t)STATE_CH * PLANE;         // 26*PLANE f32
  int*   percA  = (int*)(stateB + (size_t)STATE_CH * PLANE); // 510*510*2 i32
  int*   percB  = percA + (size_t)NEO * NEO * 2;
  float* W12    = (float*)(percB + (size_t)NEO * NEO * 2);   // 6860 f32
  float* b12    = W12 + NW;

  float* out0 = out;                           // 510*510*10
  float* out1 = out + (size_t)NEO * NEO * 10;  // 510*510*28

  prep_all<<<dim3(256 + 27), dim3(256), 0, stream>>>(state0, stateA, stateB,
                                                     W1, b1, W2, b2, W12, b12);

  dim3 grid(8, 128), block(256);
  nca_step<false><<<grid, block, 0, stream>>>(img, stateA, stateB, perc0, percB, W12, b12, nullptr, nullptr);
  nca_step<false><<<grid, block, 0, stream>>>(img, stateB, stateA, percB, percA, W12, b12, nullptr, nullptr);
  nca_step<false><<<grid, block, 0, stream>>>(img, stateA, stateB, percA, percB, W12, b12, nullptr, nullptr);
  nca_step<true ><<<grid, block, 0, stream>>>(img, stateB, nullptr, percB, nullptr, W12, b12, out0, out1);
}

// Round 11
// 324.260 us; speedup vs baseline: 1.4782x; 1.4782x over previous
//
#include <hip/hip_runtime.h>

#define NN 512
#define MM 512
#define NEO 510
#define PLANE (NN * MM)          // 262144
#define STATE_CH 26
#define OUT_DIM 28
#define FEAT 245
#define NW (FEAT * OUT_DIM)      // 6860
#define THRESH 0.0007f

// Fused prologue. blockIdx.x < 256: transpose state0 -> planar A and B.
// blockIdx.x >= 256: W12 = W1@W2, b12 = b1@W2+b2.
__global__ __launch_bounds__(256) void prep_all(
    const float* __restrict__ s0, float* __restrict__ A, float* __restrict__ B,
    const float* __restrict__ W1, const float* __restrict__ b1,
    const float* __restrict__ W2, const float* __restrict__ b2,
    float* __restrict__ W12, float* __restrict__ b12) {
  if (blockIdx.x < 256) {
    const int base = (blockIdx.x * 256 + threadIdx.x) * 4;  // 4 consecutive cells
    float v[4][STATE_CH];
    const float* src = s0 + (size_t)base * STATE_CH;
#pragma unroll
    for (int q = 0; q < 4; ++q)
#pragma unroll
      for (int c = 0; c < STATE_CH; ++c) v[q][c] = src[q * STATE_CH + c];
#pragma unroll
    for (int c = 0; c < STATE_CH; ++c) {
      float4 w = make_float4(v[0][c], v[1][c], v[2][c], v[3][c]);
      *(float4*)(A + (size_t)c * PLANE + base) = w;
      *(float4*)(B + (size_t)c * PLANE + base) = w;
    }
  } else {
    const int t = (blockIdx.x - 256) * 256 + threadIdx.x;
    if (t < NW) {
      const int f = t / OUT_DIM, k = t - f * OUT_DIM;
      float s = 0.0f;
      for (int jj = 0; jj < FEAT; ++jj) s = fmaf(W1[f * FEAT + jj], W2[jj * OUT_DIM + k], s);
      W12[t] = s;
    } else if (t < NW + OUT_DIM) {
      const int k = t - NW;
      float s = b2[k];
      for (int jj = 0; jj < FEAT; ++jj) s = fmaf(b1[jj], W2[jj * OUT_DIM + k], s);
      b12[k] = s;
    }
  }
}

// Load one (di,dj) pass's 27 feature values: img at perception window + 26 state channels.
#define LOADV(V, RP, IP)                                             \
  {                                                                  \
    V[0] = *(IP);                                                    \
    _Pragma("unroll") for (int c = 0; c < STATE_CH; ++c)             \
        V[1 + c] = (RP)[c * PLANE];                                  \
  }

// 27x28 FMA block for one pass; weight address is wave-uniform -> scalar loads.
#define FMABLK(V, WP)                                                \
  {                                                                  \
    _Pragma("unroll") for (int t = 0; t < 27; ++t) {                 \
      const float vt = V[t];                                         \
      _Pragma("unroll") for (int k = 0; k < OUT_DIM; ++k)            \
          acc[k] = fmaf(vt, (WP)[t * OUT_DIM + k], acc[k]);          \
    }                                                                \
  }

#define ADVANCE()                                                    \
  {                                                                  \
    const int d = (djc == 2) ? (MM - 2) : 1;                         \
    djc = (djc == 2) ? 0 : djc + 1;                                  \
    rp += d; ip += d;                                                \
  }

template <bool LAST>
__global__ __launch_bounds__(256, 4) void nca_step(
    const float* __restrict__ img, const float* __restrict__ sold, float* __restrict__ snew,
    const int* __restrict__ pold, int* __restrict__ pnew,
    const float* __restrict__ W12, const float* __restrict__ b12,
    float* __restrict__ out0, float* __restrict__ out1) {
  // XCD swizzle: 1024 blocks, 8 XCDs -> each XCD gets a contiguous 64-row band
  // (64*512*26*4B = 3.4 MB state <= 4 MB per-XCD L2, so di re-reads hit L2).
  const int bid = (int)blockIdx.x;
  const int lin = (bid & 7) * 128 + (bid >> 3);
  const int ib = lin >> 3;                 // row band (4 rows each)
  const int jb = lin & 7;                  // col band (64 cols each)
  const int lane = (int)(threadIdx.x & 63);
  const int wv   = (int)(threadIdx.x >> 6);
  const int i = ib * 4 + wv;
  const int j = jb * 64 + lane;
  if (i >= NEO || j >= NEO) return;
  const int cell = i * NEO + j;
  const int2 p = ((const int2*)pold)[cell];

  float acc[OUT_DIM];
#pragma unroll
  for (int k = 0; k < OUT_DIM; ++k) acc[k] = b12[k];

  const float* rp = sold + i * MM + j;     // state window base (channel 0)
  const float* ip = img + p.x * MM + p.y;  // perception window base
  const float* wp = W12;
  int djc = 0;
  float va[27], vb[27];

  LOADV(va, rp, ip);                       // pass 0
#pragma unroll 1
  for (int pr = 0; pr < 4; ++pr) {
    ADVANCE();
    LOADV(vb, rp, ip);                     // prefetch pass 2pr+1
    FMABLK(va, wp); wp += 27 * OUT_DIM;    // consume pass 2pr
    ADVANCE();
    LOADV(va, rp, ip);                     // prefetch pass 2pr+2
    FMABLK(vb, wp); wp += 27 * OUT_DIM;    // consume pass 2pr+1
  }
  FMABLK(va, wp); wp += 27 * OUT_DIM;      // pass 8

  const float posx = (float)(p.x - 256) * (1.0f / 256.0f);
  const float posy = (float)(p.y - 256) * (1.0f / 256.0f);
#pragma unroll
  for (int k = 0; k < OUT_DIM; ++k) acc[k] = fmaf(posx, wp[k], acc[k]);
#pragma unroll
  for (int k = 0; k < OUT_DIM; ++k) acc[k] = fmaf(posy, wp[OUT_DIM + k], acc[k]);

  const int nb = (i + 1) * MM + (j + 1);   // center cell in state arrays
  if (!LAST) {
    const float ax = acc[26], ay = acc[27];
    int dx = (ax < -THRESH) ? -1 : ((ax > THRESH) ? 1 : 0);
    int dy = (ay < -THRESH) ? -1 : ((ay > THRESH) ? 1 : 0);
    int nx = min(max(p.x + dx, 0), NEO - 1);
    int ny = min(max(p.y + dy, 0), NEO - 1);
    ((int2*)pnew)[cell] = make_int2(nx, ny);
#pragma unroll
    for (int c = 0; c < STATE_CH; ++c)
      snew[c * PLANE + nb] = sold[c * PLANE + nb] + acc[c];
  } else {
    // out0: final state slice channels 16..25, layout [i][j][c10]
    float2* o0 = (float2*)(out0 + (size_t)cell * 10);
#pragma unroll
    for (int c = 0; c < 5; ++c) {
      float2 v;
      v.x = sold[(16 + 2 * c) * PLANE + nb] + acc[16 + 2 * c];
      v.y = sold[(17 + 2 * c) * PLANE + nb] + acc[17 + 2 * c];
      o0[c] = v;
    }
    // out1: final guesses, layout [cell][28]
    float4* o1 = (float4*)(out1 + (size_t)cell * OUT_DIM);
#pragma unroll
    for (int q = 0; q < 7; ++q)
      o1[q] = make_float4(acc[4 * q], acc[4 * q + 1], acc[4 * q + 2], acc[4 * q + 3]);
  }
}

extern "C" void kernel_launch(void* const* d_in, const int* in_sizes, int n_in,
                              void* d_out, int out_size, void* d_ws, size_t ws_size,
                              hipStream_t stream) {
  const float* img    = (const float*)d_in[0];
  const float* state0 = (const float*)d_in[1];
  const int*   perc0  = (const int*)d_in[2];
  const float* W1     = (const float*)d_in[3];
  const float* b1     = (const float*)d_in[4];
  const float* W2     = (const float*)d_in[5];
  const float* b2     = (const float*)d_in[6];
  float* out = (float*)d_out;

  float* stateA = (float*)d_ws;                              // 26*PLANE f32
  float* stateB = stateA + (size_t)STATE_CH * PLANE;         // 26*PLANE f32
  int*   percA  = (int*)(stateB + (size_t)STATE_CH * PLANE); // 510*510*2 i32
  int*   percB  = percA + (size_t)NEO * NEO * 2;
  float* W12    = (float*)(percB + (size_t)NEO * NEO * 2);   // 6860 f32
  float* b12    = W12 + NW;

  float* out0 = out;                           // 510*510*10
  float* out1 = out + (size_t)NEO * NEO * 10;  // 510*510*28

  prep_all<<<dim3(256 + 27), dim3(256), 0, stream>>>(state0, stateA, stateB,
                                                     W1, b1, W2, b2, W12, b12);

  dim3 grid(1024), block(256);
  nca_step<false><<<grid, block, 0, stream>>>(img, stateA, stateB, perc0, percB, W12, b12, nullptr, nullptr);
  nca_step<false><<<grid, block, 0, stream>>>(img, stateB, stateA, percB, percA, W12, b12, nullptr, nullptr);
  nca_step<false><<<grid, block, 0, stream>>>(img, stateA, stateB, percA, percB, W12, b12, nullptr, nullptr);
  nca_step<true ><<<grid, block, 0, stream>>>(img, stateB, nullptr, percB, nullptr, W12, b12, out0, out1);
}